// Round 16
// baseline (486.037 us; speedup 1.0000x reference)
//
#include <hip/hip_runtime.h>
#include <hip/hip_bf16.h>

using bf16 = __hip_bfloat16;
typedef __attribute__((ext_vector_type(8))) short short8;
typedef __attribute__((ext_vector_type(4))) short sh4;
typedef __attribute__((ext_vector_type(4))) float f32x4;

#define B_ 4
#define T_ 2048
#define C_ 1024
#define H_ 16
#define FF_ 4096
#define M_TOK (B_ * T_)   // 8192
#define SCALE2 0.1803368801111f   // 0.125 * log2(e)

#define BARRIER() asm volatile("s_barrier" ::: "memory")
#define WAITLGKM0() asm volatile("s_waitcnt lgkmcnt(0)" ::: "memory")
#define WAITLGKM8() asm volatile("s_waitcnt lgkmcnt(8)" ::: "memory")
#define WAITVM4() asm volatile("s_waitcnt vmcnt(4)" ::: "memory")
#define WAITVM2() asm volatile("s_waitcnt vmcnt(2)" ::: "memory")
#define WAITVM0() asm volatile("s_waitcnt vmcnt(0)" ::: "memory")

#define SAE (256 * 64)
#define SBE256 (256 * 64)
#define SBE128 (128 * 64)
#define HALF256 (128 * 64)

// ---------------- async global->LDS 16B ----------------
__device__ __forceinline__ void gload16(const void* g, void* l) {
    __builtin_amdgcn_global_load_lds(
        (const __attribute__((address_space(1))) void*)g,
        (__attribute__((address_space(3))) void*)l, 16, 0, 0);
}

// 2^x in one instruction
__device__ __forceinline__ float fexp2(float x) {
    float r;
    asm("v_exp_f32 %0, %1" : "=v"(r) : "v"(x));
    return r;
}

__device__ __forceinline__ float bf16bits2f(short s) {
    return __uint_as_float(((unsigned)(unsigned short)s) << 16);
}

// pack two f32 -> one dword of 2 bf16
__device__ __forceinline__ unsigned bf2(float a, float b) {
    bf16 x = __float2bfloat16(a), y = __float2bfloat16(b);
    unsigned short ux = *(unsigned short*)&x, uy = *(unsigned short*)&y;
    return (unsigned)ux | ((unsigned)uy << 16);
}

// fast gelu
__device__ __forceinline__ float fgelu(float x) {
    float y = 0.79788456f * (x + 0.044715f * x * x * x);
    float tv = fexp2(y * 2.885390082f);
    return x * tv * __builtin_amdgcn_rcpf(tv + 1.f);
}

// ---------------- prep: LN1 (blocks 0..8191) + w_attn cvt only ----------------
__global__ __launch_bounds__(256) void prep_kernel(
    const float* __restrict__ x, const float* __restrict__ ln1w, const float* __restrict__ ln1b,
    bf16* __restrict__ ln_out,
    const float* __restrict__ w_attn, bf16* __restrict__ wattn_h) {
    const int bid = blockIdx.x;
    const int t = threadIdx.x;
    if (bid < M_TOK) {
        float4 v = ((const float4*)(x + (size_t)bid * C_))[t];
        float s = v.x + v.y + v.z + v.w;
        float s2 = v.x * v.x + v.y * v.y + v.z * v.z + v.w * v.w;
#pragma unroll
        for (int off = 32; off > 0; off >>= 1) {
            s += __shfl_down(s, off);
            s2 += __shfl_down(s2, off);
        }
        __shared__ float ss[4], ss2[4];
        int wave = t >> 6, lane = t & 63;
        if (lane == 0) { ss[wave] = s; ss2[wave] = s2; }
        __syncthreads();
        s = ss[0] + ss[1] + ss[2] + ss[3];
        s2 = ss2[0] + ss2[1] + ss2[2] + ss2[3];
        float mu = s * (1.f / C_);
        float var = s2 * (1.f / C_) - mu * mu;
        float rstd = rsqrtf(var + 1e-5f);
        float4 wv = ((const float4*)ln1w)[t];
        float4 bv = ((const float4*)ln1b)[t];
        uint2 o;
        o.x = bf2((v.x - mu) * rstd * wv.x + bv.x, (v.y - mu) * rstd * wv.y + bv.y);
        o.y = bf2((v.z - mu) * rstd * wv.z + bv.z, (v.w - mu) * rstd * wv.w + bv.w);
        ((uint2*)(ln_out + (size_t)bid * C_))[t] = o;
    } else {
        int j = (bid - M_TOK) * 256 + t;
        float4 v = ((const float4*)w_attn)[j];
        uint2 o;
        o.x = bf2(v.x, v.y);
        o.y = bf2(v.z, v.w);
        ((uint2*)wattn_h)[j] = o;
    }
}

// ---------------- LayerNorm (LN2): bf16 in -> bf16 out ----------------
__global__ __launch_bounds__(256) void ln_kernel_b(const bf16* __restrict__ x,
                                                   const float* __restrict__ w,
                                                   const float* __restrict__ b,
                                                   bf16* __restrict__ out) {
    int row = blockIdx.x;
    int t = threadIdx.x;
    sh4 h = ((const sh4*)(x + (size_t)row * C_))[t];
    float4 v;
    v.x = bf16bits2f(h[0]);
    v.y = bf16bits2f(h[1]);
    v.z = bf16bits2f(h[2]);
    v.w = bf16bits2f(h[3]);
    float s = v.x + v.y + v.z + v.w;
    float s2 = v.x * v.x + v.y * v.y + v.z * v.z + v.w * v.w;
#pragma unroll
    for (int off = 32; off > 0; off >>= 1) {
        s += __shfl_down(s, off);
        s2 += __shfl_down(s2, off);
    }
    __shared__ float ss[4], ss2[4];
    int wave = t >> 6, lane = t & 63;
    if (lane == 0) { ss[wave] = s; ss2[wave] = s2; }
    __syncthreads();
    s = ss[0] + ss[1] + ss[2] + ss[3];
    s2 = ss2[0] + ss2[1] + ss2[2] + ss2[3];
    float mu = s * (1.f / C_);
    float var = s2 * (1.f / C_) - mu * mu;
    float rstd = rsqrtf(var + 1e-5f);
    float4 wv = ((const float4*)w)[t];
    float4 bv = ((const float4*)b)[t];
    uint2 o;
    o.x = bf2((v.x - mu) * rstd * wv.x + bv.x, (v.y - mu) * rstd * wv.y + bv.y);
    o.y = bf2((v.z - mu) * rstd * wv.z + bv.z, (v.w - mu) * rstd * wv.w + bv.w);
    ((uint2*)(out + (size_t)row * C_))[t] = o;
}

// ======== shared staging macro ========
#define STG(ldsbase, g, grow0, k0)                                               \
    {                                                                            \
        _Pragma("unroll") for (int s_ = 0; s_ < 2; s_++) {                       \
            int row_ = s_ * 64 + wid * 8 + sr;                                   \
            gload16(g + (size_t)((grow0) + row_) * K + (k0) + ssc,               \
                    (ldsbase) + row_ * 64 + (lane & 7) * 8);                     \
        }                                                                        \
    }

// ---------------- 256x256 8-phase NT GEMM body ----------------
template <int EPI>
__device__ __forceinline__ void gemm256_dev(short* SAp, short* SBp, int bid,
                                            const bf16* __restrict__ Ag,
                                            const bf16* __restrict__ Bg,
                                            void* __restrict__ Cout,
                                            int M, int N, int K) {
    const int nbx = N >> 8;
    const int nwg = nbx * (M >> 8);
    const int cpx = nwg >> 3;
    const int swzb = (bid & 7) * cpx + (bid >> 3);
    const int m0 = (swzb / nbx) * 256;
    const int n0 = (swzb % nbx) * 256;

    const int t = threadIdx.x;
    const int wid = t >> 6, lane = t & 63;
    const int wm = wid >> 2, wn = wid & 3;
    const int lrow = lane & 15, lg = lane >> 4;
    const int swzr = (lane & 7) * 8;
    const int sr = lane >> 3;
    const int ssc = ((lane & 7) ^ sr) * 8;

    f32x4 acc[8][4];
#pragma unroll
    for (int mi = 0; mi < 8; mi++)
#pragma unroll
        for (int ni = 0; ni < 4; ni++) acc[mi][ni] = (f32x4){0.f, 0.f, 0.f, 0.f};
    short8 bfr[4][2];

    const int T = K >> 6;
    const int niter = T >> 1;

#define DSREADS256(q, buf)                                                       \
    if ((q) == 0) {                                                              \
        _Pragma("unroll") for (int ni = 0; ni < 4; ni++)                         \
        _Pragma("unroll") for (int ks = 0; ks < 2; ks++)                         \
            bfr[ni][ks] = *(const short8*)(&SBp[(buf) * SBE256 +                 \
                (wn * 64 + ni * 16 + lrow) * 64 + ((ks * 32 + lg * 8) ^ swzr)]); \
    }                                                                            \
    _Pragma("unroll") for (int mi2 = 0; mi2 < 2; mi2++)                          \
    _Pragma("unroll") for (int ks = 0; ks < 2; ks++)                             \
        af[mi2 * 2 + ks] = *(const short8*)(&SAp[(buf) * SAE +                   \
            (wm * 128 + (2 * (q) + mi2) * 16 + lrow) * 64 + ((ks * 32 + lg * 8) ^ swzr)]);

#define MFMAS256(q)                                                              \
    __builtin_amdgcn_s_setprio(1);                                               \
    _Pragma("unroll") for (int ks = 0; ks < 2; ks++)                             \
    _Pragma("unroll") for (int ni = 0; ni < 4; ni++)                             \
    _Pragma("unroll") for (int mi2 = 0; mi2 < 2; mi2++)                          \
        acc[2 * (q) + mi2][ni] = __builtin_amdgcn_mfma_f32_16x16x32_bf16(        \
            bfr[ni][ks], af[mi2 * 2 + ks], acc[2 * (q) + mi2][ni], 0, 0, 0);     \
    __builtin_amdgcn_s_setprio(0);

    STG(SAp, Ag, m0, 0);
    STG(SAp + HALF256, Ag, m0 + 128, 0);
    STG(SBp, Bg, n0, 0);
    STG(SBp + HALF256, Bg, n0 + 128, 0);
    STG(SBp + SBE256, Bg, n0, 64);
    STG(SBp + SBE256 + HALF256, Bg, n0 + 128, 64);
    WAITVM4();
    BARRIER();

    for (int iter = 0; iter < niter; iter++) {
        const int tt = 2 * iter;
        const int ka = (tt + 1) * 64, kb = (tt + 2) * 64, kc = (tt + 3) * 64;
        const bool s2 = (tt + 2 < T), s3 = (tt + 3 < T);
        const bool last = (iter == niter - 1);
        short8 af[4];

        DSREADS256(0, 0);
        STG(SAp + SAE, Ag, m0, ka);
        WAITLGKM8();
        BARRIER(); WAITLGKM0(); MFMAS256(0); BARRIER();
        DSREADS256(1, 0);
        STG(SAp + SAE + HALF256, Ag, m0 + 128, ka);
        BARRIER(); WAITLGKM0(); MFMAS256(1); BARRIER();
        DSREADS256(2, 0);
        if (s2) STG(SBp, Bg, n0, kb);
        BARRIER(); WAITLGKM0(); MFMAS256(2); BARRIER();
        DSREADS256(3, 0);
        if (s2) STG(SBp + HALF256, Bg, n0 + 128, kb);
        BARRIER(); WAITLGKM0(); MFMAS256(3);
        if (last) { WAITVM0(); } else { WAITVM4(); }
        BARRIER();
        DSREADS256(0, 1);
        if (s2) STG(SAp, Ag, m0, kb);
        WAITLGKM8();
        BARRIER(); WAITLGKM0(); MFMAS256(0); BARRIER();
        DSREADS256(1, 1);
        if (s2) STG(SAp + HALF256, Ag, m0 + 128, kb);
        BARRIER(); WAITLGKM0(); MFMAS256(1); BARRIER();
        DSREADS256(2, 1);
        if (s3) STG(SBp + SBE256, Bg, n0, kc);
        BARRIER(); WAITLGKM0(); MFMAS256(2); BARRIER();
        DSREADS256(3, 1);
        if (s3) STG(SBp + SBE256 + HALF256, Bg, n0 + 128, kc);
        BARRIER(); WAITLGKM0(); MFMAS256(3);
        if (!last) WAITVM4();
        BARRIER();
    }

#pragma unroll
    for (int mi = 0; mi < 8; mi++) {
        const int gm = m0 + wm * 128 + mi * 16 + lrow;
#pragma unroll
        for (int ni = 0; ni < 4; ni++) {
            const int gn = n0 + wn * 64 + ni * 16 + lg * 4;
            size_t gi = (size_t)gm * N + gn;
            f32x4 a = acc[mi][ni];
            if constexpr (EPI == 0) {
                uint2 o; o.x = bf2(a[0], a[1]); o.y = bf2(a[2], a[3]);
                *(uint2*)&(((bf16*)Cout)[gi]) = o;
            } else if constexpr (EPI == 5) {
                float sc = (gn < C_) ? SCALE2 : 1.f;
                uint2 o; o.x = bf2(a[0] * sc, a[1] * sc); o.y = bf2(a[2] * sc, a[3] * sc);
                *(uint2*)&(((bf16*)Cout)[gi]) = o;
            } else {
                uint2 o;
                o.x = bf2(fgelu(a[0]), fgelu(a[1]));
                o.y = bf2(fgelu(a[2]), fgelu(a[3]));
                *(uint2*)&(((bf16*)Cout)[gi]) = o;
            }
        }
    }
}

// ---------------- 256x128 8-phase NT GEMM body ----------------
template <int EPI>
__device__ __forceinline__ void gemm256x128_dev(short* SAp, short* SBp, int bid,
                                                const bf16* __restrict__ Ag,
                                                const bf16* __restrict__ Bg,
                                                void* __restrict__ Cout,
                                                const void* __restrict__ Res,
                                                int M, int N, int K) {
    const int nbx = N >> 7;
    const int nwg = nbx * (M >> 8);
    const int cpx = nwg >> 3;
    const int swzb = (bid & 7) * cpx + (bid >> 3);
    const int m0 = (swzb / nbx) * 256;
    const int n0 = (swzb % nbx) * 128;

    const int t = threadIdx.x;
    const int wid = t >> 6, lane = t & 63;
    const int wm = wid >> 1, wn = wid & 1;
    const int lrow = lane & 15, lg = lane >> 4;
    const int swzr = (lane & 7) * 8;
    const int sr = lane >> 3;
    const int ssc = ((lane & 7) ^ sr) * 8;

    f32x4 acc[4][4];
#pragma unroll
    for (int mi = 0; mi < 4; mi++)
#pragma unroll
        for (int ni = 0; ni < 4; ni++) acc[mi][ni] = (f32x4){0.f, 0.f, 0.f, 0.f};
    short8 bfr[4][2];

    const int T = K >> 6;
    const int niter = T >> 1;

#define DSRX(p, buf)                                                             \
    if ((p) == 0) {                                                              \
        _Pragma("unroll") for (int ni = 0; ni < 4; ni++)                         \
        _Pragma("unroll") for (int ks = 0; ks < 2; ks++)                         \
            bfr[ni][ks] = *(const short8*)(&SBp[(buf) * SBE128 +                 \
                (wn * 64 + ni * 16 + lrow) * 64 + ((ks * 32 + lg * 8) ^ swzr)]); \
    }                                                                            \
    _Pragma("unroll") for (int mi2 = 0; mi2 < 2; mi2++)                          \
    _Pragma("unroll") for (int ks = 0; ks < 2; ks++)                             \
        af[mi2 * 2 + ks] = *(const short8*)(&SAp[(buf) * SAE +                   \
            (wm * 64 + (2 * (p) + mi2) * 16 + lrow) * 64 + ((ks * 32 + lg * 8) ^ swzr)]);

#define MFX(p)                                                                   \
    __builtin_amdgcn_s_setprio(1);                                               \
    _Pragma("unroll") for (int ks = 0; ks < 2; ks++)                             \
    _Pragma("unroll") for (int ni = 0; ni < 4; ni++)                             \
    _Pragma("unroll") for (int mi2 = 0; mi2 < 2; mi2++)                          \
        acc[2 * (p) + mi2][ni] = __builtin_amdgcn_mfma_f32_16x16x32_bf16(        \
            bfr[ni][ks], af[mi2 * 2 + ks], acc[2 * (p) + mi2][ni], 0, 0, 0);     \
    __builtin_amdgcn_s_setprio(0);

    STG(SAp, Ag, m0, 0);
    STG(SAp + HALF256, Ag, m0 + 128, 0);
    STG(SBp, Bg, n0, 0);
    STG(SBp + SBE128, Bg, n0, 64);
    WAITVM2();
    BARRIER();

    for (int iter = 0; iter < niter; iter++) {
        const int tt = 2 * iter;
        const int ka = (tt + 1) * 64, kb = (tt + 2) * 64, kc = (tt + 3) * 64;
        const bool s2 = (tt + 2 < T), s3 = (tt + 3 < T);
        const bool last = (iter == niter - 1);
        short8 af[4];

        DSRX(0, 0);
        STG(SAp + SAE, Ag, m0, ka);
        STG(SAp + SAE + HALF256, Ag, m0 + 128, ka);
        WAITLGKM8();
        BARRIER(); WAITLGKM0(); MFX(0); BARRIER();
        DSRX(1, 0);
        if (s2) STG(SBp, Bg, n0, kb);
        BARRIER(); WAITLGKM0(); MFX(1);
        if (last) { WAITVM0(); } else { WAITVM2(); }
        BARRIER();
        DSRX(0, 1);
        if (s2) {
            STG(SAp, Ag, m0, kb);
            STG(SAp + HALF256, Ag, m0 + 128, kb);
        }
        WAITLGKM8();
        BARRIER(); WAITLGKM0(); MFX(0); BARRIER();
        DSRX(1, 1);
        if (s3) STG(SBp + SBE128, Bg, n0, kc);
        BARRIER(); WAITLGKM0(); MFX(1);
        if (last) { WAITVM0(); } else { WAITVM2(); }
        BARRIER();
    }

#pragma unroll
    for (int mi = 0; mi < 4; mi++) {
        const int gm = m0 + wm * 64 + mi * 16 + lrow;
#pragma unroll
        for (int ni = 0; ni < 4; ni++) {
            const int gn = n0 + wn * 64 + ni * 16 + lg * 4;
            size_t gi = (size_t)gm * N + gn;
            f32x4 a = acc[mi][ni];
            if constexpr (EPI == 0) {
                uint2 o; o.x = bf2(a[0], a[1]); o.y = bf2(a[2], a[3]);
                *(uint2*)&(((bf16*)Cout)[gi]) = o;
            } else if constexpr (EPI == 3) {
                float4 rv = *(const float4*)&(((const float*)Res)[gi]);
                uint2 o; o.x = bf2(rv.x + a[0], rv.y + a[1]); o.y = bf2(rv.z + a[2], rv.w + a[3]);
                *(uint2*)&(((bf16*)Cout)[gi]) = o;
            } else {
                sh4 hv = *(const sh4*)&(((const bf16*)Res)[gi]);
                float4 o;
                o.x = bf16bits2f(hv[0]) + a[0];
                o.y = bf16bits2f(hv[1]) + a[1];
                o.z = bf16bits2f(hv[2]) + a[2];
                o.w = bf16bits2f(hv[3]) + a[3];
                *(float4*)&(((float*)Cout)[gi]) = o;
            }
        }
    }
}

// ---------------- kernel wrappers ----------------
template <int EPI>
__global__ __launch_bounds__(512, 2) void gemm256(const bf16* __restrict__ Ag,
                                                  const bf16* __restrict__ Bg,
                                                  void* __restrict__ Cout,
                                                  int M, int N, int K) {
    __shared__ short LDS[2 * SAE + 2 * SBE256];
    gemm256_dev<EPI>(LDS, LDS + 2 * SAE, blockIdx.x, Ag, Bg, Cout, M, N, K);
}

template <int EPI>
__global__ __launch_bounds__(512, 2) void gemm256x128(const bf16* __restrict__ Ag,
                                                      const bf16* __restrict__ Bg,
                                                      void* __restrict__ Cout,
                                                      const void* __restrict__ Res,
                                                      int M, int N, int K) {
    __shared__ short LDS[2 * SAE + 2 * SBE128];
    gemm256x128_dev<EPI>(LDS, LDS + 2 * SAE, blockIdx.x, Ag, Bg, Cout, Res, M, N, K);
}

// merged qk (blocks 0..255) + vt (blocks 256..511)
__global__ __launch_bounds__(512, 2) void gemm_qkvt(const bf16* __restrict__ ln_buf,
                                                    const bf16* __restrict__ wattn_h,
                                                    bf16* __restrict__ qk_buf,
                                                    bf16* __restrict__ vt_buf) {
    __shared__ short LDS[2 * SAE + 2 * SBE256];
    if (blockIdx.x < 256) {
        gemm256_dev<5>(LDS, LDS + 2 * SAE, blockIdx.x,
                       ln_buf, wattn_h, qk_buf, M_TOK, 2 * C_, C_);
    } else {
        gemm256x128_dev<0>(LDS, LDS + 2 * SAE, blockIdx.x - 256,
                           wattn_h + (size_t)2 * C_ * C_, ln_buf, vt_buf, nullptr,
                           C_, M_TOK, C_);
    }
}

// ---------------- flash attention (blocks 0..1023) + deferred weight cvt (blocks 1024+) ----------------
// LDS [64][64] shorts, XOR-swizzled; 24 KB/block -> 6 blocks/CU with launch_bounds(256,6)
__global__ __launch_bounds__(256, 6) void flash_cvt(const bf16* __restrict__ qk,
                                                    const bf16* __restrict__ vt,
                                                    bf16* __restrict__ y,
                                                    const float* __restrict__ w_proj,
                                                    const float* __restrict__ w_fc,
                                                    const float* __restrict__ w_fcp,
                                                    bf16* __restrict__ wproj_h,
                                                    bf16* __restrict__ wfc_h,
                                                    bf16* __restrict__ wfcp_h) {
    const int bid = blockIdx.x;
    const int t = threadIdx.x;

    if (bid >= 1024) {
        int i = (bid - 1024) * 256 + t;
        const float* src;
        bf16* dst;
        int base;
        if (i < 262144) {            // w_proj: C*C/4
            src = w_proj; dst = wproj_h; base = 0;
        } else if (i < 1310720) {    // w_fc: FF*C/4
            src = w_fc; dst = wfc_h; base = 262144;
        } else {                     // w_fcp: C*FF/4
            src = w_fcp; dst = wfcp_h; base = 1310720;
        }
        int j = i - base;
        float4 v = ((const float4*)src)[j];
        uint2 o;
        o.x = bf2(v.x, v.y);
        o.y = bf2(v.z, v.w);
        ((uint2*)dst)[j] = o;
        return;
    }

    const int bh = bid & 63;
    const int pi = bid >> 6;
    const int b = bh >> 4, h = bh & 15;
    const int wave = t >> 6, lane = t & 63;
    const int lrow = lane & 15, lg = lane >> 4, lk = lg * 8;
    const int swz = (lrow & 7) * 8;

    __shared__ alignas(16) short Ks[64 * 64];
    __shared__ alignas(16) short Vs[64 * 64];
    __shared__ alignas(16) short Ps[64 * 64];

    const size_t rs = 2 * C_;
    const bf16* Qg = qk + (size_t)b * T_ * rs + h * 64;
    const bf16* Kg = Qg + C_;
    const bf16* Vg = vt + (size_t)(h * 64) * M_TOK + b * T_;

    const int srow = t >> 3;
    const int sc8 = (t & 7) * 8;
    const int ssw = sc8 ^ ((srow & 7) * 8);

    const int ql = pi, qh = 31 - pi;
    const int nkt = qh + 1;
    const int qgH = qh * 64 + wave * 16 + lrow;
    const int qgL = ql * 64 + wave * 16 + lrow;

    short8 qfH[2], qfL[2];
    {
        const bf16* qr = Qg + (size_t)qgH * rs;
        qfH[0] = *(const short8*)(qr + lk);
        qfH[1] = *(const short8*)(qr + 32 + lk);
        qr = Qg + (size_t)qgL * rs;
        qfL[0] = *(const short8*)(qr + lk);
        qfL[1] = *(const short8*)(qr + 32 + lk);
    }

    f32x4 oH[4], oL[4];
    float mH = -1e30f, lH = 0.f, mL = -1e30f, lL = 0.f;
#pragma unroll
    for (int ni = 0; ni < 4; ni++) {
        oH[ni] = (f32x4){0.f, 0.f, 0.f, 0.f};
        oL[ni] = (f32x4){0.f, 0.f, 0.f, 0.f};
    }

    short8 kr[2], vr[2];
#pragma unroll
    for (int p = 0; p < 2; p++) {
        int r = srow + p * 32;
        kr[p] = *(const short8*)(Kg + (size_t)r * rs + sc8);
        vr[p] = *(const short8*)(Vg + (size_t)r * M_TOK + sc8);
    }

    for (int kt = 0; kt < nkt; kt++) {
        const int s0 = kt * 64;
#pragma unroll
        for (int p = 0; p < 2; p++) {
            int r = srow + p * 32;
            *(short8*)(&Ks[r * 64 + ssw]) = kr[p];
            *(short8*)(&Vs[r * 64 + ssw]) = vr[p];
        }
        __syncthreads();
        if (kt + 1 < nkt) {
            const int s0n = (kt + 1) * 64;
#pragma unroll
            for (int p = 0; p < 2; p++) {
                int r = srow + p * 32;
                kr[p] = *(const short8*)(Kg + (size_t)(s0n + r) * rs + sc8);
                vr[p] = *(const short8*)(Vg + (size_t)r * M_TOK + s0n + sc8);
            }
        }

        // ======== HEAVY tile ========
        {
            f32x4 s[4];
#pragma unroll
            for (int ni = 0; ni < 4; ni++) s[ni] = (f32x4){0.f, 0.f, 0.f, 0.f};
            __builtin_amdgcn_s_setprio(1);
#pragma unroll
            for (int ks = 0; ks < 2; ks++)
#pragma unroll
                for (int ni = 0; ni < 4; ni++) {
                    short8 kf = *(const short8*)(&Ks[(ni * 16 + lrow) * 64 + ((ks * 32 + lk) ^ swz)]);
                    s[ni] = __builtin_amdgcn_mfma_f32_16x16x32_bf16(kf, qfH[ks], s[ni], 0, 0, 0);
                }
            __builtin_amdgcn_s_setprio(0);

            if (kt == qh) {
#pragma unroll
                for (int ni = 0; ni < 4; ni++)
#pragma unroll
                    for (int r = 0; r < 4; r++) {
                        int kvg = s0 + ni * 16 + lg * 4 + r;
                        if (kvg > qgH) s[ni][r] = -1e30f;
                    }
            }

            float pm = s[0][0];
#pragma unroll
            for (int ni = 0; ni < 4; ni++)
#pragma unroll
                for (int r = 0; r < 4; r++) pm = fmaxf(pm, s[ni][r]);
            pm = fmaxf(pm, __shfl_xor(pm, 16));
            pm = fmaxf(pm, __shfl_xor(pm, 32));
            if (!__all(pm - mH <= 8.f)) {
                float mn = fmaxf(mH, pm);
                float alpha = fexp2(mH - mn);
                mH = mn;
                lH *= alpha;
#pragma unroll
                for (int ni = 0; ni < 4; ni++)
#pragma unroll
                    for (int r = 0; r < 4; r++) oH[ni][r] *= alpha;
            }
            float rsum = 0.f;
#pragma unroll
            for (int ni = 0; ni < 4; ni++) {
                float p0 = fexp2(s[ni][0] - mH);
                float p1 = fexp2(s[ni][1] - mH);
                float p2 = fexp2(s[ni][2] - mH);
                float p3 = fexp2(s[ni][3] - mH);
                rsum += (p0 + p1) + (p2 + p3);
                uint2 pk; pk.x = bf2(p0, p1); pk.y = bf2(p2, p3);
                *(uint2*)(&Ps[(wave * 16 + lrow) * 64 + ((ni * 16 + lg * 4) ^ swz)]) = pk;
            }
            rsum += __shfl_xor(rsum, 16);
            rsum += __shfl_xor(rsum, 32);
            lH += rsum;

            __builtin_amdgcn_s_setprio(1);
#pragma unroll
            for (int ks2 = 0; ks2 < 2; ks2++) {
                short8 pf = *(const short8*)(&Ps[(wave * 16 + lrow) * 64 + ((ks2 * 32 + lk) ^ swz)]);
#pragma unroll
                for (int ni = 0; ni < 4; ni++) {
                    short8 vf = *(const short8*)(&Vs[(ni * 16 + lrow) * 64 + ((ks2 * 32 + lk) ^ swz)]);
                    oH[ni] = __builtin_amdgcn_mfma_f32_16x16x32_bf16(vf, pf, oH[ni], 0, 0, 0);
                }
            }
            __builtin_amdgcn_s_setprio(0);
        }

        // ======== LIGHT tile (shares staged K/V) ========
        if (kt <= ql) {
            f32x4 s[4];
#pragma unroll
            for (int ni = 0; ni < 4; ni++) s[ni] = (f32x4){0.f, 0.f, 0.f, 0.f};
            __builtin_amdgcn_s_setprio(1);
#pragma unroll
            for (int ks = 0; ks < 2; ks++)
#pragma unroll
                for (int ni = 0; ni < 4; ni++) {
                    short8 kf = *(const short8*)(&Ks[(ni * 16 + lrow) * 64 + ((ks * 32 + lk) ^ swz)]);
                    s[ni] = __builtin_amdgcn_mfma_f32_16x16x32_bf16(kf, qfL[ks], s[ni], 0, 0, 0);
                }
            __builtin_amdgcn_s_setprio(0);

            if (kt == ql) {
#pragma unroll
                for (int ni = 0; ni < 4; ni++)
#pragma unroll
                    for (int r = 0; r < 4; r++) {
                        int kvg = s0 + ni * 16 + lg * 4 + r;
                        if (kvg > qgL) s[ni][r] = -1e30f;
                    }
            }

            float pm = s[0][0];
#pragma unroll
            for (int ni = 0; ni < 4; ni++)
#pragma unroll
                for (int r = 0; r < 4; r++) pm = fmaxf(pm, s[ni][r]);
            pm = fmaxf(pm, __shfl_xor(pm, 16));
            pm = fmaxf(pm, __shfl_xor(pm, 32));
            if (!__all(pm - mL <= 8.f)) {
                float mn = fmaxf(mL, pm);
                float alpha = fexp2(mL - mn);
                mL = mn;
                lL *= alpha;
#pragma unroll
                for (int ni = 0; ni < 4; ni++)
#pragma unroll
                    for (int r = 0; r < 4; r++) oL[ni][r] *= alpha;
            }
            float rsum = 0.f;
#pragma unroll
            for (int ni = 0; ni < 4; ni++) {
                float p0 = fexp2(s[ni][0] - mL);
                float p1 = fexp2(s[ni][1] - mL);
                float p2 = fexp2(s[ni][2] - mL);
                float p3 = fexp2(s[ni][3] - mL);
                rsum += (p0 + p1) + (p2 + p3);
                uint2 pk; pk.x = bf2(p0, p1); pk.y = bf2(p2, p3);
                *(uint2*)(&Ps[(wave * 16 + lrow) * 64 + ((ni * 16 + lg * 4) ^ swz)]) = pk;
            }
            rsum += __shfl_xor(rsum, 16);
            rsum += __shfl_xor(rsum, 32);
            lL += rsum;

            __builtin_amdgcn_s_setprio(1);
#pragma unroll
            for (int ks2 = 0; ks2 < 2; ks2++) {
                short8 pf = *(const short8*)(&Ps[(wave * 16 + lrow) * 64 + ((ks2 * 32 + lk) ^ swz)]);
#pragma unroll
                for (int ni = 0; ni < 4; ni++) {
                    short8 vf = *(const short8*)(&Vs[(ni * 16 + lrow) * 64 + ((ks2 * 32 + lk) ^ swz)]);
                    oL[ni] = __builtin_amdgcn_mfma_f32_16x16x32_bf16(vf, pf, oL[ni], 0, 0, 0);
                }
            }
            __builtin_amdgcn_s_setprio(0);
        }
        __syncthreads();
    }

    float invH = 1.f / lH, invL = 1.f / lL;
#pragma unroll
    for (int ni = 0; ni < 4; ni++) {
        uint2 pk;
        pk.x = bf2(oH[ni][0] * invH, oH[ni][1] * invH);
        pk.y = bf2(oH[ni][2] * invH, oH[ni][3] * invH);
        *(uint2*)(&y[((size_t)(b * T_ + qgH)) * C_ + h * 64 + ni * 16 + lg * 4]) = pk;
        pk.x = bf2(oL[ni][0] * invL, oL[ni][1] * invL);
        pk.y = bf2(oL[ni][2] * invL, oL[ni][3] * invL);
        *(uint2*)(&y[((size_t)(b * T_ + qgL)) * C_ + h * 64 + ni * 16 + lg * 4]) = pk;
    }
}

// ---------------- launch ----------------
extern "C" void kernel_launch(void* const* d_in, const int* in_sizes, int n_in,
                              void* d_out, int out_size, void* d_ws, size_t ws_size,
                              hipStream_t stream) {
    const float* x      = (const float*)d_in[0];
    const float* ln1w   = (const float*)d_in[1];
    const float* ln1b   = (const float*)d_in[2];
    const float* ln2w   = (const float*)d_in[3];
    const float* ln2b   = (const float*)d_in[4];
    const float* w_attn = (const float*)d_in[5];
    const float* w_proj = (const float*)d_in[6];
    const float* w_fc   = (const float*)d_in[7];
    const float* w_fcp  = (const float*)d_in[8];
    float* out = (float*)d_out;

    char* ws = (char*)d_ws;
    bf16* ln_buf  = (bf16*)(ws);                   // [0,16M)
    bf16* qk_buf  = (bf16*)(ws + (16u << 20));     // [16,48M)
    bf16* vt_buf  = (bf16*)(ws + (48u << 20));     // [48,64M)
    bf16* ybuf    = (bf16*)(ws + (64u << 20));     // [64,80M)
    bf16* ubuf    = (bf16*)(ws + (16u << 20));     // [16,80M) reuse after attn
    bf16* x2b     = (bf16*)(ws + (80u << 20));     // [80,96M)
    bf16* wattn_h = (bf16*)(ws + (112u << 20));
    bf16* wproj_h = (bf16*)(ws + (118u << 20));
    bf16* wfc_h   = (bf16*)(ws + (120u << 20));
    bf16* wfcp_h  = (bf16*)(ws + (128u << 20));

    // prep: LN1 + w_attn cvt only
    prep_kernel<<<M_TOK + 3072, 256, 0, stream>>>(
        x, ln1w, ln1b, ln_buf, w_attn, wattn_h);

    // merged qk + vt
    gemm_qkvt<<<512, 512, 0, stream>>>(ln_buf, wattn_h, qk_buf, vt_buf);

    // flash attention + deferred weight conversions in tail
    flash_cvt<<<1024 + 9216, 256, 0, stream>>>(
        qk_buf, vt_buf, ybuf, w_proj, w_fc, w_fcp, wproj_h, wfc_h, wfcp_h);

    // x2b = bf16(x + ybuf @ w_proj^T)
    gemm256x128<3><<<dim3((M_TOK / 256) * (C_ / 128)), 512, 0, stream>>>(
        ybuf, wproj_h, x2b, x, M_TOK, C_, C_);

    // LN2
    ln_kernel_b<<<M_TOK, 256, 0, stream>>>(x2b, ln2w, ln2b, ln_buf);

    // u = fgelu(ln_buf @ w_fc^T)
    gemm256<2><<<dim3((M_TOK / 256) * (FF_ / 256)), 512, 0, stream>>>(
        ln_buf, wfc_h, ubuf, M_TOK, FF_, C_);

    // out = f32(x2b) + u @ w_fcp^T
    gemm256x128<4><<<dim3((M_TOK / 256) * (C_ / 128)), 512, 0, stream>>>(
        ubuf, wfcp_h, out, x2b, M_TOK, C_, FF_);
}

// Round 17
// 315.784 us; speedup vs baseline: 1.5391x; 1.5391x over previous
//
#include <hip/hip_runtime.h>
#include <hip/hip_bf16.h>

using bf16 = __hip_bfloat16;
typedef __attribute__((ext_vector_type(8))) short short8;
typedef __attribute__((ext_vector_type(4))) short sh4;
typedef __attribute__((ext_vector_type(4))) float f32x4;

#define B_ 4
#define T_ 2048
#define C_ 1024
#define H_ 16
#define FF_ 4096
#define M_TOK (B_ * T_)   // 8192
#define SCALE2 0.1803368801111f   // 0.125 * log2(e)

#define BARRIER() asm volatile("s_barrier" ::: "memory")
#define WAITLGKM0() asm volatile("s_waitcnt lgkmcnt(0)" ::: "memory")
#define WAITLGKM8() asm volatile("s_waitcnt lgkmcnt(8)" ::: "memory")
#define WAITVM4() asm volatile("s_waitcnt vmcnt(4)" ::: "memory")
#define WAITVM2() asm volatile("s_waitcnt vmcnt(2)" ::: "memory")
#define WAITVM0() asm volatile("s_waitcnt vmcnt(0)" ::: "memory")

#define SAE (256 * 64)
#define SBE256 (256 * 64)
#define SBE128 (128 * 64)
#define HALF256 (128 * 64)

// ---------------- async global->LDS 16B ----------------
__device__ __forceinline__ void gload16(const void* g, void* l) {
    __builtin_amdgcn_global_load_lds(
        (const __attribute__((address_space(1))) void*)g,
        (__attribute__((address_space(3))) void*)l, 16, 0, 0);
}

// 2^x in one instruction
__device__ __forceinline__ float fexp2(float x) {
    float r;
    asm("v_exp_f32 %0, %1" : "=v"(r) : "v"(x));
    return r;
}

__device__ __forceinline__ float bf16bits2f(short s) {
    return __uint_as_float(((unsigned)(unsigned short)s) << 16);
}

// pack two f32 -> one dword of 2 bf16
__device__ __forceinline__ unsigned bf2(float a, float b) {
    bf16 x = __float2bfloat16(a), y = __float2bfloat16(b);
    unsigned short ux = *(unsigned short*)&x, uy = *(unsigned short*)&y;
    return (unsigned)ux | ((unsigned)uy << 16);
}

// fast gelu
__device__ __forceinline__ float fgelu(float x) {
    float y = 0.79788456f * (x + 0.044715f * x * x * x);
    float tv = fexp2(y * 2.885390082f);
    return x * tv * __builtin_amdgcn_rcpf(tv + 1.f);
}

// ---------------- prep: LN1 (blocks 0..8191) + w_attn cvt only ----------------
__global__ __launch_bounds__(256) void prep_kernel(
    const float* __restrict__ x, const float* __restrict__ ln1w, const float* __restrict__ ln1b,
    bf16* __restrict__ ln_out,
    const float* __restrict__ w_attn, bf16* __restrict__ wattn_h) {
    const int bid = blockIdx.x;
    const int t = threadIdx.x;
    if (bid < M_TOK) {
        float4 v = ((const float4*)(x + (size_t)bid * C_))[t];
        float s = v.x + v.y + v.z + v.w;
        float s2 = v.x * v.x + v.y * v.y + v.z * v.z + v.w * v.w;
#pragma unroll
        for (int off = 32; off > 0; off >>= 1) {
            s += __shfl_down(s, off);
            s2 += __shfl_down(s2, off);
        }
        __shared__ float ss[4], ss2[4];
        int wave = t >> 6, lane = t & 63;
        if (lane == 0) { ss[wave] = s; ss2[wave] = s2; }
        __syncthreads();
        s = ss[0] + ss[1] + ss[2] + ss[3];
        s2 = ss2[0] + ss2[1] + ss2[2] + ss2[3];
        float mu = s * (1.f / C_);
        float var = s2 * (1.f / C_) - mu * mu;
        float rstd = rsqrtf(var + 1e-5f);
        float4 wv = ((const float4*)ln1w)[t];
        float4 bv = ((const float4*)ln1b)[t];
        uint2 o;
        o.x = bf2((v.x - mu) * rstd * wv.x + bv.x, (v.y - mu) * rstd * wv.y + bv.y);
        o.y = bf2((v.z - mu) * rstd * wv.z + bv.z, (v.w - mu) * rstd * wv.w + bv.w);
        ((uint2*)(ln_out + (size_t)bid * C_))[t] = o;
    } else {
        int j = (bid - M_TOK) * 256 + t;
        float4 v = ((const float4*)w_attn)[j];
        uint2 o;
        o.x = bf2(v.x, v.y);
        o.y = bf2(v.z, v.w);
        ((uint2*)wattn_h)[j] = o;
    }
}

// ---------------- LayerNorm (LN2): bf16 in -> bf16 out ----------------
__global__ __launch_bounds__(256) void ln_kernel_b(const bf16* __restrict__ x,
                                                   const float* __restrict__ w,
                                                   const float* __restrict__ b,
                                                   bf16* __restrict__ out) {
    int row = blockIdx.x;
    int t = threadIdx.x;
    sh4 h = ((const sh4*)(x + (size_t)row * C_))[t];
    float4 v;
    v.x = bf16bits2f(h[0]);
    v.y = bf16bits2f(h[1]);
    v.z = bf16bits2f(h[2]);
    v.w = bf16bits2f(h[3]);
    float s = v.x + v.y + v.z + v.w;
    float s2 = v.x * v.x + v.y * v.y + v.z * v.z + v.w * v.w;
#pragma unroll
    for (int off = 32; off > 0; off >>= 1) {
        s += __shfl_down(s, off);
        s2 += __shfl_down(s2, off);
    }
    __shared__ float ss[4], ss2[4];
    int wave = t >> 6, lane = t & 63;
    if (lane == 0) { ss[wave] = s; ss2[wave] = s2; }
    __syncthreads();
    s = ss[0] + ss[1] + ss[2] + ss[3];
    s2 = ss2[0] + ss2[1] + ss2[2] + ss2[3];
    float mu = s * (1.f / C_);
    float var = s2 * (1.f / C_) - mu * mu;
    float rstd = rsqrtf(var + 1e-5f);
    float4 wv = ((const float4*)w)[t];
    float4 bv = ((const float4*)b)[t];
    uint2 o;
    o.x = bf2((v.x - mu) * rstd * wv.x + bv.x, (v.y - mu) * rstd * wv.y + bv.y);
    o.y = bf2((v.z - mu) * rstd * wv.z + bv.z, (v.w - mu) * rstd * wv.w + bv.w);
    ((uint2*)(out + (size_t)row * C_))[t] = o;
}

// ======== shared staging macro ========
#define STG(ldsbase, g, grow0, k0)                                               \
    {                                                                            \
        _Pragma("unroll") for (int s_ = 0; s_ < 2; s_++) {                       \
            int row_ = s_ * 64 + wid * 8 + sr;                                   \
            gload16(g + (size_t)((grow0) + row_) * K + (k0) + ssc,               \
                    (ldsbase) + row_ * 64 + (lane & 7) * 8);                     \
        }                                                                        \
    }

// ---------------- 256x256 8-phase NT GEMM body ----------------
template <int EPI>
__device__ __forceinline__ void gemm256_dev(short* SAp, short* SBp, int bid,
                                            const bf16* __restrict__ Ag,
                                            const bf16* __restrict__ Bg,
                                            void* __restrict__ Cout,
                                            int M, int N, int K) {
    const int nbx = N >> 8;
    const int nwg = nbx * (M >> 8);
    const int cpx = nwg >> 3;
    const int swzb = (bid & 7) * cpx + (bid >> 3);
    const int m0 = (swzb / nbx) * 256;
    const int n0 = (swzb % nbx) * 256;

    const int t = threadIdx.x;
    const int wid = t >> 6, lane = t & 63;
    const int wm = wid >> 2, wn = wid & 3;
    const int lrow = lane & 15, lg = lane >> 4;
    const int swzr = (lane & 7) * 8;
    const int sr = lane >> 3;
    const int ssc = ((lane & 7) ^ sr) * 8;

    f32x4 acc[8][4];
#pragma unroll
    for (int mi = 0; mi < 8; mi++)
#pragma unroll
        for (int ni = 0; ni < 4; ni++) acc[mi][ni] = (f32x4){0.f, 0.f, 0.f, 0.f};
    short8 bfr[4][2];

    const int T = K >> 6;
    const int niter = T >> 1;

#define DSREADS256(q, buf)                                                       \
    if ((q) == 0) {                                                              \
        _Pragma("unroll") for (int ni = 0; ni < 4; ni++)                         \
        _Pragma("unroll") for (int ks = 0; ks < 2; ks++)                         \
            bfr[ni][ks] = *(const short8*)(&SBp[(buf) * SBE256 +                 \
                (wn * 64 + ni * 16 + lrow) * 64 + ((ks * 32 + lg * 8) ^ swzr)]); \
    }                                                                            \
    _Pragma("unroll") for (int mi2 = 0; mi2 < 2; mi2++)                          \
    _Pragma("unroll") for (int ks = 0; ks < 2; ks++)                             \
        af[mi2 * 2 + ks] = *(const short8*)(&SAp[(buf) * SAE +                   \
            (wm * 128 + (2 * (q) + mi2) * 16 + lrow) * 64 + ((ks * 32 + lg * 8) ^ swzr)]);

#define MFMAS256(q)                                                              \
    __builtin_amdgcn_s_setprio(1);                                               \
    _Pragma("unroll") for (int ks = 0; ks < 2; ks++)                             \
    _Pragma("unroll") for (int ni = 0; ni < 4; ni++)                             \
    _Pragma("unroll") for (int mi2 = 0; mi2 < 2; mi2++)                          \
        acc[2 * (q) + mi2][ni] = __builtin_amdgcn_mfma_f32_16x16x32_bf16(        \
            bfr[ni][ks], af[mi2 * 2 + ks], acc[2 * (q) + mi2][ni], 0, 0, 0);     \
    __builtin_amdgcn_s_setprio(0);

    STG(SAp, Ag, m0, 0);
    STG(SAp + HALF256, Ag, m0 + 128, 0);
    STG(SBp, Bg, n0, 0);
    STG(SBp + HALF256, Bg, n0 + 128, 0);
    STG(SBp + SBE256, Bg, n0, 64);
    STG(SBp + SBE256 + HALF256, Bg, n0 + 128, 64);
    WAITVM4();
    BARRIER();

    for (int iter = 0; iter < niter; iter++) {
        const int tt = 2 * iter;
        const int ka = (tt + 1) * 64, kb = (tt + 2) * 64, kc = (tt + 3) * 64;
        const bool s2 = (tt + 2 < T), s3 = (tt + 3 < T);
        const bool last = (iter == niter - 1);
        short8 af[4];

        DSREADS256(0, 0);
        STG(SAp + SAE, Ag, m0, ka);
        WAITLGKM8();
        BARRIER(); WAITLGKM0(); MFMAS256(0); BARRIER();
        DSREADS256(1, 0);
        STG(SAp + SAE + HALF256, Ag, m0 + 128, ka);
        BARRIER(); WAITLGKM0(); MFMAS256(1); BARRIER();
        DSREADS256(2, 0);
        if (s2) STG(SBp, Bg, n0, kb);
        BARRIER(); WAITLGKM0(); MFMAS256(2); BARRIER();
        DSREADS256(3, 0);
        if (s2) STG(SBp + HALF256, Bg, n0 + 128, kb);
        BARRIER(); WAITLGKM0(); MFMAS256(3);
        if (last) { WAITVM0(); } else { WAITVM4(); }
        BARRIER();
        DSREADS256(0, 1);
        if (s2) STG(SAp, Ag, m0, kb);
        WAITLGKM8();
        BARRIER(); WAITLGKM0(); MFMAS256(0); BARRIER();
        DSREADS256(1, 1);
        if (s2) STG(SAp + HALF256, Ag, m0 + 128, kb);
        BARRIER(); WAITLGKM0(); MFMAS256(1); BARRIER();
        DSREADS256(2, 1);
        if (s3) STG(SBp + SBE256, Bg, n0, kc);
        BARRIER(); WAITLGKM0(); MFMAS256(2); BARRIER();
        DSREADS256(3, 1);
        if (s3) STG(SBp + SBE256 + HALF256, Bg, n0 + 128, kc);
        BARRIER(); WAITLGKM0(); MFMAS256(3);
        if (!last) WAITVM4();
        BARRIER();
    }

#pragma unroll
    for (int mi = 0; mi < 8; mi++) {
        const int gm = m0 + wm * 128 + mi * 16 + lrow;
#pragma unroll
        for (int ni = 0; ni < 4; ni++) {
            const int gn = n0 + wn * 64 + ni * 16 + lg * 4;
            size_t gi = (size_t)gm * N + gn;
            f32x4 a = acc[mi][ni];
            if constexpr (EPI == 0) {
                uint2 o; o.x = bf2(a[0], a[1]); o.y = bf2(a[2], a[3]);
                *(uint2*)&(((bf16*)Cout)[gi]) = o;
            } else if constexpr (EPI == 5) {
                float sc = (gn < C_) ? SCALE2 : 1.f;
                uint2 o; o.x = bf2(a[0] * sc, a[1] * sc); o.y = bf2(a[2] * sc, a[3] * sc);
                *(uint2*)&(((bf16*)Cout)[gi]) = o;
            } else {
                uint2 o;
                o.x = bf2(fgelu(a[0]), fgelu(a[1]));
                o.y = bf2(fgelu(a[2]), fgelu(a[3]));
                *(uint2*)&(((bf16*)Cout)[gi]) = o;
            }
        }
    }
}

// ---------------- 256x128 8-phase NT GEMM body ----------------
template <int EPI>
__device__ __forceinline__ void gemm256x128_dev(short* SAp, short* SBp, int bid,
                                                const bf16* __restrict__ Ag,
                                                const bf16* __restrict__ Bg,
                                                void* __restrict__ Cout,
                                                const void* __restrict__ Res,
                                                int M, int N, int K) {
    const int nbx = N >> 7;
    const int nwg = nbx * (M >> 8);
    const int cpx = nwg >> 3;
    const int swzb = (bid & 7) * cpx + (bid >> 3);
    const int m0 = (swzb / nbx) * 256;
    const int n0 = (swzb % nbx) * 128;

    const int t = threadIdx.x;
    const int wid = t >> 6, lane = t & 63;
    const int wm = wid >> 1, wn = wid & 1;
    const int lrow = lane & 15, lg = lane >> 4;
    const int swzr = (lane & 7) * 8;
    const int sr = lane >> 3;
    const int ssc = ((lane & 7) ^ sr) * 8;

    f32x4 acc[4][4];
#pragma unroll
    for (int mi = 0; mi < 4; mi++)
#pragma unroll
        for (int ni = 0; ni < 4; ni++) acc[mi][ni] = (f32x4){0.f, 0.f, 0.f, 0.f};
    short8 bfr[4][2];

    const int T = K >> 6;
    const int niter = T >> 1;

#define DSRX(p, buf)                                                             \
    if ((p) == 0) {                                                              \
        _Pragma("unroll") for (int ni = 0; ni < 4; ni++)                         \
        _Pragma("unroll") for (int ks = 0; ks < 2; ks++)                         \
            bfr[ni][ks] = *(const short8*)(&SBp[(buf) * SBE128 +                 \
                (wn * 64 + ni * 16 + lrow) * 64 + ((ks * 32 + lg * 8) ^ swzr)]); \
    }                                                                            \
    _Pragma("unroll") for (int mi2 = 0; mi2 < 2; mi2++)                          \
    _Pragma("unroll") for (int ks = 0; ks < 2; ks++)                             \
        af[mi2 * 2 + ks] = *(const short8*)(&SAp[(buf) * SAE +                   \
            (wm * 64 + (2 * (p) + mi2) * 16 + lrow) * 64 + ((ks * 32 + lg * 8) ^ swzr)]);

#define MFX(p)                                                                   \
    __builtin_amdgcn_s_setprio(1);                                               \
    _Pragma("unroll") for (int ks = 0; ks < 2; ks++)                             \
    _Pragma("unroll") for (int ni = 0; ni < 4; ni++)                             \
    _Pragma("unroll") for (int mi2 = 0; mi2 < 2; mi2++)                          \
        acc[2 * (p) + mi2][ni] = __builtin_amdgcn_mfma_f32_16x16x32_bf16(        \
            bfr[ni][ks], af[mi2 * 2 + ks], acc[2 * (p) + mi2][ni], 0, 0, 0);     \
    __builtin_amdgcn_s_setprio(0);

    STG(SAp, Ag, m0, 0);
    STG(SAp + HALF256, Ag, m0 + 128, 0);
    STG(SBp, Bg, n0, 0);
    STG(SBp + SBE128, Bg, n0, 64);
    WAITVM2();
    BARRIER();

    for (int iter = 0; iter < niter; iter++) {
        const int tt = 2 * iter;
        const int ka = (tt + 1) * 64, kb = (tt + 2) * 64, kc = (tt + 3) * 64;
        const bool s2 = (tt + 2 < T), s3 = (tt + 3 < T);
        const bool last = (iter == niter - 1);
        short8 af[4];

        DSRX(0, 0);
        STG(SAp + SAE, Ag, m0, ka);
        STG(SAp + SAE + HALF256, Ag, m0 + 128, ka);
        WAITLGKM8();
        BARRIER(); WAITLGKM0(); MFX(0); BARRIER();
        DSRX(1, 0);
        if (s2) STG(SBp, Bg, n0, kb);
        BARRIER(); WAITLGKM0(); MFX(1);
        if (last) { WAITVM0(); } else { WAITVM2(); }
        BARRIER();
        DSRX(0, 1);
        if (s2) {
            STG(SAp, Ag, m0, kb);
            STG(SAp + HALF256, Ag, m0 + 128, kb);
        }
        WAITLGKM8();
        BARRIER(); WAITLGKM0(); MFX(0); BARRIER();
        DSRX(1, 1);
        if (s3) STG(SBp + SBE128, Bg, n0, kc);
        BARRIER(); WAITLGKM0(); MFX(1);
        if (last) { WAITVM0(); } else { WAITVM2(); }
        BARRIER();
    }

#pragma unroll
    for (int mi = 0; mi < 4; mi++) {
        const int gm = m0 + wm * 64 + mi * 16 + lrow;
#pragma unroll
        for (int ni = 0; ni < 4; ni++) {
            const int gn = n0 + wn * 64 + ni * 16 + lg * 4;
            size_t gi = (size_t)gm * N + gn;
            f32x4 a = acc[mi][ni];
            if constexpr (EPI == 0) {
                uint2 o; o.x = bf2(a[0], a[1]); o.y = bf2(a[2], a[3]);
                *(uint2*)&(((bf16*)Cout)[gi]) = o;
            } else if constexpr (EPI == 3) {
                float4 rv = *(const float4*)&(((const float*)Res)[gi]);
                uint2 o; o.x = bf2(rv.x + a[0], rv.y + a[1]); o.y = bf2(rv.z + a[2], rv.w + a[3]);
                *(uint2*)&(((bf16*)Cout)[gi]) = o;
            } else {
                sh4 hv = *(const sh4*)&(((const bf16*)Res)[gi]);
                float4 o;
                o.x = bf16bits2f(hv[0]) + a[0];
                o.y = bf16bits2f(hv[1]) + a[1];
                o.z = bf16bits2f(hv[2]) + a[2];
                o.w = bf16bits2f(hv[3]) + a[3];
                *(float4*)&(((float*)Cout)[gi]) = o;
            }
        }
    }
}

// ---------------- kernel wrappers ----------------
template <int EPI>
__global__ __launch_bounds__(512, 2) void gemm256(const bf16* __restrict__ Ag,
                                                  const bf16* __restrict__ Bg,
                                                  void* __restrict__ Cout,
                                                  int M, int N, int K) {
    __shared__ short LDS[2 * SAE + 2 * SBE256];
    gemm256_dev<EPI>(LDS, LDS + 2 * SAE, blockIdx.x, Ag, Bg, Cout, M, N, K);
}

template <int EPI>
__global__ __launch_bounds__(512, 2) void gemm256x128(const bf16* __restrict__ Ag,
                                                      const bf16* __restrict__ Bg,
                                                      void* __restrict__ Cout,
                                                      const void* __restrict__ Res,
                                                      int M, int N, int K) {
    __shared__ short LDS[2 * SAE + 2 * SBE128];
    gemm256x128_dev<EPI>(LDS, LDS + 2 * SAE, blockIdx.x, Ag, Bg, Cout, Res, M, N, K);
}

// merged qk (blocks 0..255) + vt (blocks 256..511)
__global__ __launch_bounds__(512, 2) void gemm_qkvt(const bf16* __restrict__ ln_buf,
                                                    const bf16* __restrict__ wattn_h,
                                                    bf16* __restrict__ qk_buf,
                                                    bf16* __restrict__ vt_buf) {
    __shared__ short LDS[2 * SAE + 2 * SBE256];
    if (blockIdx.x < 256) {
        gemm256_dev<5>(LDS, LDS + 2 * SAE, blockIdx.x,
                       ln_buf, wattn_h, qk_buf, M_TOK, 2 * C_, C_);
    } else {
        gemm256x128_dev<0>(LDS, LDS + 2 * SAE, blockIdx.x - 256,
                           wattn_h + (size_t)2 * C_ * C_, ln_buf, vt_buf, nullptr,
                           C_, M_TOK, C_);
    }
}

// ---------------- flash attention (blocks 0..1023) + deferred weight cvt (blocks 1024+) ----------------
// LDS [64][64] shorts, XOR-swizzled; launch_bounds(256,4) — (256,6) caps VGPR at ~42 and spills (round 16)
__global__ __launch_bounds__(256, 4) void flash_cvt(const bf16* __restrict__ qk,
                                                    const bf16* __restrict__ vt,
                                                    bf16* __restrict__ y,
                                                    const float* __restrict__ w_proj,
                                                    const float* __restrict__ w_fc,
                                                    const float* __restrict__ w_fcp,
                                                    bf16* __restrict__ wproj_h,
                                                    bf16* __restrict__ wfc_h,
                                                    bf16* __restrict__ wfcp_h) {
    const int bid = blockIdx.x;
    const int t = threadIdx.x;

    if (bid >= 1024) {
        int i = (bid - 1024) * 256 + t;
        const float* src;
        bf16* dst;
        int base;
        if (i < 262144) {            // w_proj: C*C/4
            src = w_proj; dst = wproj_h; base = 0;
        } else if (i < 1310720) {    // w_fc: FF*C/4
            src = w_fc; dst = wfc_h; base = 262144;
        } else {                     // w_fcp: C*FF/4
            src = w_fcp; dst = wfcp_h; base = 1310720;
        }
        int j = i - base;
        float4 v = ((const float4*)src)[j];
        uint2 o;
        o.x = bf2(v.x, v.y);
        o.y = bf2(v.z, v.w);
        ((uint2*)dst)[j] = o;
        return;
    }

    const int bh = bid & 63;
    const int pi = bid >> 6;
    const int b = bh >> 4, h = bh & 15;
    const int wave = t >> 6, lane = t & 63;
    const int lrow = lane & 15, lg = lane >> 4, lk = lg * 8;
    const int swz = (lrow & 7) * 8;

    __shared__ alignas(16) short Ks[64 * 64];
    __shared__ alignas(16) short Vs[64 * 64];
    __shared__ alignas(16) short Ps[64 * 64];

    const size_t rs = 2 * C_;
    const bf16* Qg = qk + (size_t)b * T_ * rs + h * 64;
    const bf16* Kg = Qg + C_;
    const bf16* Vg = vt + (size_t)(h * 64) * M_TOK + b * T_;

    const int srow = t >> 3;
    const int sc8 = (t & 7) * 8;
    const int ssw = sc8 ^ ((srow & 7) * 8);

    const int ql = pi, qh = 31 - pi;
    const int nkt = qh + 1;
    const int qgH = qh * 64 + wave * 16 + lrow;
    const int qgL = ql * 64 + wave * 16 + lrow;

    short8 qfH[2], qfL[2];
    {
        const bf16* qr = Qg + (size_t)qgH * rs;
        qfH[0] = *(const short8*)(qr + lk);
        qfH[1] = *(const short8*)(qr + 32 + lk);
        qr = Qg + (size_t)qgL * rs;
        qfL[0] = *(const short8*)(qr + lk);
        qfL[1] = *(const short8*)(qr + 32 + lk);
    }

    f32x4 oH[4], oL[4];
    float mH = -1e30f, lH = 0.f, mL = -1e30f, lL = 0.f;
#pragma unroll
    for (int ni = 0; ni < 4; ni++) {
        oH[ni] = (f32x4){0.f, 0.f, 0.f, 0.f};
        oL[ni] = (f32x4){0.f, 0.f, 0.f, 0.f};
    }

    short8 kr[2], vr[2];
#pragma unroll
    for (int p = 0; p < 2; p++) {
        int r = srow + p * 32;
        kr[p] = *(const short8*)(Kg + (size_t)r * rs + sc8);
        vr[p] = *(const short8*)(Vg + (size_t)r * M_TOK + sc8);
    }

    for (int kt = 0; kt < nkt; kt++) {
        const int s0 = kt * 64;
#pragma unroll
        for (int p = 0; p < 2; p++) {
            int r = srow + p * 32;
            *(short8*)(&Ks[r * 64 + ssw]) = kr[p];
            *(short8*)(&Vs[r * 64 + ssw]) = vr[p];
        }
        __syncthreads();
        if (kt + 1 < nkt) {
            const int s0n = (kt + 1) * 64;
#pragma unroll
            for (int p = 0; p < 2; p++) {
                int r = srow + p * 32;
                kr[p] = *(const short8*)(Kg + (size_t)(s0n + r) * rs + sc8);
                vr[p] = *(const short8*)(Vg + (size_t)r * M_TOK + s0n + sc8);
            }
        }

        // ======== HEAVY tile ========
        {
            f32x4 s[4];
#pragma unroll
            for (int ni = 0; ni < 4; ni++) s[ni] = (f32x4){0.f, 0.f, 0.f, 0.f};
            __builtin_amdgcn_s_setprio(1);
#pragma unroll
            for (int ks = 0; ks < 2; ks++)
#pragma unroll
                for (int ni = 0; ni < 4; ni++) {
                    short8 kf = *(const short8*)(&Ks[(ni * 16 + lrow) * 64 + ((ks * 32 + lk) ^ swz)]);
                    s[ni] = __builtin_amdgcn_mfma_f32_16x16x32_bf16(kf, qfH[ks], s[ni], 0, 0, 0);
                }
            __builtin_amdgcn_s_setprio(0);

            if (kt == qh) {
#pragma unroll
                for (int ni = 0; ni < 4; ni++)
#pragma unroll
                    for (int r = 0; r < 4; r++) {
                        int kvg = s0 + ni * 16 + lg * 4 + r;
                        if (kvg > qgH) s[ni][r] = -1e30f;
                    }
            }

            float pm = s[0][0];
#pragma unroll
            for (int ni = 0; ni < 4; ni++)
#pragma unroll
                for (int r = 0; r < 4; r++) pm = fmaxf(pm, s[ni][r]);
            pm = fmaxf(pm, __shfl_xor(pm, 16));
            pm = fmaxf(pm, __shfl_xor(pm, 32));
            if (!__all(pm - mH <= 8.f)) {
                float mn = fmaxf(mH, pm);
                float alpha = fexp2(mH - mn);
                mH = mn;
                lH *= alpha;
#pragma unroll
                for (int ni = 0; ni < 4; ni++)
#pragma unroll
                    for (int r = 0; r < 4; r++) oH[ni][r] *= alpha;
            }
            float rsum = 0.f;
#pragma unroll
            for (int ni = 0; ni < 4; ni++) {
                float p0 = fexp2(s[ni][0] - mH);
                float p1 = fexp2(s[ni][1] - mH);
                float p2 = fexp2(s[ni][2] - mH);
                float p3 = fexp2(s[ni][3] - mH);
                rsum += (p0 + p1) + (p2 + p3);
                uint2 pk; pk.x = bf2(p0, p1); pk.y = bf2(p2, p3);
                *(uint2*)(&Ps[(wave * 16 + lrow) * 64 + ((ni * 16 + lg * 4) ^ swz)]) = pk;
            }
            rsum += __shfl_xor(rsum, 16);
            rsum += __shfl_xor(rsum, 32);
            lH += rsum;

            __builtin_amdgcn_s_setprio(1);
#pragma unroll
            for (int ks2 = 0; ks2 < 2; ks2++) {
                short8 pf = *(const short8*)(&Ps[(wave * 16 + lrow) * 64 + ((ks2 * 32 + lk) ^ swz)]);
#pragma unroll
                for (int ni = 0; ni < 4; ni++) {
                    short8 vf = *(const short8*)(&Vs[(ni * 16 + lrow) * 64 + ((ks2 * 32 + lk) ^ swz)]);
                    oH[ni] = __builtin_amdgcn_mfma_f32_16x16x32_bf16(vf, pf, oH[ni], 0, 0, 0);
                }
            }
            __builtin_amdgcn_s_setprio(0);
        }

        // ======== LIGHT tile (shares staged K/V) ========
        if (kt <= ql) {
            f32x4 s[4];
#pragma unroll
            for (int ni = 0; ni < 4; ni++) s[ni] = (f32x4){0.f, 0.f, 0.f, 0.f};
            __builtin_amdgcn_s_setprio(1);
#pragma unroll
            for (int ks = 0; ks < 2; ks++)
#pragma unroll
                for (int ni = 0; ni < 4; ni++) {
                    short8 kf = *(const short8*)(&Ks[(ni * 16 + lrow) * 64 + ((ks * 32 + lk) ^ swz)]);
                    s[ni] = __builtin_amdgcn_mfma_f32_16x16x32_bf16(kf, qfL[ks], s[ni], 0, 0, 0);
                }
            __builtin_amdgcn_s_setprio(0);

            if (kt == ql) {
#pragma unroll
                for (int ni = 0; ni < 4; ni++)
#pragma unroll
                    for (int r = 0; r < 4; r++) {
                        int kvg = s0 + ni * 16 + lg * 4 + r;
                        if (kvg > qgL) s[ni][r] = -1e30f;
                    }
            }

            float pm = s[0][0];
#pragma unroll
            for (int ni = 0; ni < 4; ni++)
#pragma unroll
                for (int r = 0; r < 4; r++) pm = fmaxf(pm, s[ni][r]);
            pm = fmaxf(pm, __shfl_xor(pm, 16));
            pm = fmaxf(pm, __shfl_xor(pm, 32));
            if (!__all(pm - mL <= 8.f)) {
                float mn = fmaxf(mL, pm);
                float alpha = fexp2(mL - mn);
                mL = mn;
                lL *= alpha;
#pragma unroll
                for (int ni = 0; ni < 4; ni++)
#pragma unroll
                    for (int r = 0; r < 4; r++) oL[ni][r] *= alpha;
            }
            float rsum = 0.f;
#pragma unroll
            for (int ni = 0; ni < 4; ni++) {
                float p0 = fexp2(s[ni][0] - mL);
                float p1 = fexp2(s[ni][1] - mL);
                float p2 = fexp2(s[ni][2] - mL);
                float p3 = fexp2(s[ni][3] - mL);
                rsum += (p0 + p1) + (p2 + p3);
                uint2 pk; pk.x = bf2(p0, p1); pk.y = bf2(p2, p3);
                *(uint2*)(&Ps[(wave * 16 + lrow) * 64 + ((ni * 16 + lg * 4) ^ swz)]) = pk;
            }
            rsum += __shfl_xor(rsum, 16);
            rsum += __shfl_xor(rsum, 32);
            lL += rsum;

            __builtin_amdgcn_s_setprio(1);
#pragma unroll
            for (int ks2 = 0; ks2 < 2; ks2++) {
                short8 pf = *(const short8*)(&Ps[(wave * 16 + lrow) * 64 + ((ks2 * 32 + lk) ^ swz)]);
#pragma unroll
                for (int ni = 0; ni < 4; ni++) {
                    short8 vf = *(const short8*)(&Vs[(ni * 16 + lrow) * 64 + ((ks2 * 32 + lk) ^ swz)]);
                    oL[ni] = __builtin_amdgcn_mfma_f32_16x16x32_bf16(vf, pf, oL[ni], 0, 0, 0);
                }
            }
            __builtin_amdgcn_s_setprio(0);
        }
        __syncthreads();
    }

    float invH = 1.f / lH, invL = 1.f / lL;
#pragma unroll
    for (int ni = 0; ni < 4; ni++) {
        uint2 pk;
        pk.x = bf2(oH[ni][0] * invH, oH[ni][1] * invH);
        pk.y = bf2(oH[ni][2] * invH, oH[ni][3] * invH);
        *(uint2*)(&y[((size_t)(b * T_ + qgH)) * C_ + h * 64 + ni * 16 + lg * 4]) = pk;
        pk.x = bf2(oL[ni][0] * invL, oL[ni][1] * invL);
        pk.y = bf2(oL[ni][2] * invL, oL[ni][3] * invL);
        *(uint2*)(&y[((size_t)(b * T_ + qgL)) * C_ + h * 64 + ni * 16 + lg * 4]) = pk;
    }
}

// ---------------- launch ----------------
extern "C" void kernel_launch(void* const* d_in, const int* in_sizes, int n_in,
                              void* d_out, int out_size, void* d_ws, size_t ws_size,
                              hipStream_t stream) {
    const float* x      = (const float*)d_in[0];
    const float* ln1w   = (const float*)d_in[1];
    const float* ln1b   = (const float*)d_in[2];
    const float* ln2w   = (const float*)d_in[3];
    const float* ln2b   = (const float*)d_in[4];
    const float* w_attn = (const float*)d_in[5];
    const float* w_proj = (const float*)d_in[6];
    const float* w_fc   = (const float*)d_in[7];
    const float* w_fcp  = (const float*)d_in[8];
    float* out = (float*)d_out;

    char* ws = (char*)d_ws;
    bf16* ln_buf  = (bf16*)(ws);                   // [0,16M)
    bf16* qk_buf  = (bf16*)(ws + (16u << 20));     // [16,48M)
    bf16* vt_buf  = (bf16*)(ws + (48u << 20));     // [48,64M)
    bf16* ybuf    = (bf16*)(ws + (64u << 20));     // [64,80M)
    bf16* ubuf    = (bf16*)(ws + (16u << 20));     // [16,80M) reuse after attn
    bf16* x2b     = (bf16*)(ws + (80u << 20));     // [80,96M)
    bf16* wattn_h = (bf16*)(ws + (112u << 20));
    bf16* wproj_h = (bf16*)(ws + (118u << 20));
    bf16* wfc_h   = (bf16*)(ws + (120u << 20));
    bf16* wfcp_h  = (bf16*)(ws + (128u << 20));

    // prep: LN1 + w_attn cvt only
    prep_kernel<<<M_TOK + 3072, 256, 0, stream>>>(
        x, ln1w, ln1b, ln_buf, w_attn, wattn_h);

    // merged qk + vt
    gemm_qkvt<<<512, 512, 0, stream>>>(ln_buf, wattn_h, qk_buf, vt_buf);

    // flash attention + deferred weight conversions in tail
    flash_cvt<<<1024 + 9216, 256, 0, stream>>>(
        qk_buf, vt_buf, ybuf, w_proj, w_fc, w_fcp, wproj_h, wfc_h, wfcp_h);

    // x2b = bf16(x + ybuf @ w_proj^T)
    gemm256x128<3><<<dim3((M_TOK / 256) * (C_ / 128)), 512, 0, stream>>>(
        ybuf, wproj_h, x2b, x, M_TOK, C_, C_);

    // LN2
    ln_kernel_b<<<M_TOK, 256, 0, stream>>>(x2b, ln2w, ln2b, ln_buf);

    // u = fgelu(ln_buf @ w_fc^T)
    gemm256<2><<<dim3((M_TOK / 256) * (FF_ / 256)), 512, 0, stream>>>(
        ln_buf, wfc_h, ubuf, M_TOK, FF_, C_);

    // out = f32(x2b) + u @ w_fcp^T
    gemm256x128<4><<<dim3((M_TOK / 256) * (C_ / 128)), 512, 0, stream>>>(
        ubuf, wfcp_h, out, x2b, M_TOK, C_, FF_);
}